// Round 6
// baseline (1485.959 us; speedup 1.0000x reference)
//
#include <hip/hip_runtime.h>
#include <hip/hip_bf16.h>
#include <math.h>

typedef unsigned short u16;
typedef __bf16 bf16x8 __attribute__((ext_vector_type(8)));
typedef float f32x4 __attribute__((ext_vector_type(4)));

#define M_ROWS 50176      // B*H*W = 64*28*28
#define ATTN_ROWS 6272    // 8 batches per chunk = 49 * 128
#define ATTN_WINS 128     // windows per chunk
#define SCALE_ 0.17677669529663687f

__device__ __forceinline__ float bf2f(u16 x){
  union { unsigned u; float f; } c; c.u = ((unsigned)x) << 16; return c.f;
}
__device__ __forceinline__ u16 f2bf(float f){
  union { float f; unsigned u; } c; c.f = f;
  unsigned u = c.u;
  u += 0x7fffu + ((u >> 16) & 1u);   // RNE
  return (u16)(u >> 16);
}
// isbf: 1 -> array is bf16, 0 -> fp32
__device__ __forceinline__ float ldf(const void* p, size_t i, int isbf){
  return isbf ? bf2f(((const u16*)p)[i]) : ((const float*)p)[i];
}

// ---- per-input dtype probe (proven in r5: fp32 detected for all nonzero inputs;
// all-zero arrays default to bf16 which reads zeros -> value-correct either way) ----
struct Ptrs { const void* p[14]; int sz[14]; };
__global__ __launch_bounds__(64) void probe_dtypes(Ptrs ps, int* flags){
  int i = blockIdx.x;
  const unsigned* w = (const unsigned*)ps.p[i];
  int nw = ps.sz[i] >> 1;
  if (nw < 1) nw = 1;
  int stride = nw >> 6; if (!stride) stride = 1;
  int lane = threadIdx.x;
  long idx = (long)lane * stride; if (idx >= nw) idx = nw - 1;
  unsigned v = w[idx];
  unsigned L = v & 0xFFFFu;
  int lexp = (int)((L >> 7) & 0xFF);
  bool vb = (L != 0) && (lexp >= 100) && (lexp <= 141);
  bool vf = (!vb) && (v != 0);
  unsigned long long mb = __ballot(vb), mf = __ballot(vf);
  if (lane == 0) flags[i] = (__popcll(mb) >= __popcll(mf)) ? 1 : 0;
}

// ---- param conversion: all 1-D inputs -> fp32 block in ws ----
// floats: qkv_b@0(1152) proj_b@1152(384) fc1_b@1536(1536) fc2_b@3072(384)
//         n1g@3456 n1b@3840 n2g@4224 n2b@4608 (384 each) rpb@4992(2028) -> 7020
__global__ void cvt_all(const void* qkv_b, const void* proj_b, const void* fc1_b, const void* fc2_b,
                        const void* n1g, const void* n1b, const void* n2g, const void* n2b,
                        const void* rpb, const int* __restrict__ flags, float* dst){
  int i = blockIdx.x * 256 + threadIdx.x;
  if (i >= 7020) return;
  const void* src; int loc, fi;
  if      (i < 1152){ src = qkv_b; loc = i;        fi = 2; }
  else if (i < 1536){ src = proj_b; loc = i - 1152; fi = 4; }
  else if (i < 3072){ src = fc1_b; loc = i - 1536; fi = 11; }
  else if (i < 3456){ src = fc2_b; loc = i - 3072; fi = 13; }
  else if (i < 3840){ src = n1g;  loc = i - 3456; fi = 6; }
  else if (i < 4224){ src = n1b;  loc = i - 3840; fi = 7; }
  else if (i < 4608){ src = n2g;  loc = i - 4224; fi = 8; }
  else if (i < 4992){ src = n2b;  loc = i - 4608; fi = 9; }
  else              { src = rpb;  loc = i - 4992; fi = 5; }
  dst[i] = ldf(src, loc, flags[fi]);
}

// ---- weight transpose: in (K,N) either dtype -> out (N,K) bf16 ----
__global__ void transpose_k(const void* __restrict__ in, u16* __restrict__ out, int K, int N,
                            const int* __restrict__ flags, int fi){
  int tid = blockIdx.x * 256 + threadIdx.x;
  if (tid < K * N){
    int n = tid / K, k = tid - n * K;
    out[tid] = f2bf(ldf(in, (size_t)k * N + n, flags[fi]));
  }
}

// ---- LN1 + shift + window partition for one 8-batch chunk ----
__global__ __launch_bounds__(128) void ln1_kernel(const void* __restrict__ x, const float* __restrict__ g,
                                                  const float* __restrict__ bt, u16* __restrict__ xw,
                                                  const int* __restrict__ flags, int row0, int win0){
  int row = row0 + blockIdx.x;
  int bf = flags[0];
  size_t base = (size_t)row * 384;
  int t = threadIdx.x;
  float v0 = ldf(x, base + t, bf), v1 = ldf(x, base + t + 128, bf), v2 = ldf(x, base + t + 256, bf);
  float s = v0+v1+v2;
  float q = v0*v0+v1*v1+v2*v2;
  #pragma unroll
  for (int off = 32; off; off >>= 1){ s += __shfl_down(s, off); q += __shfl_down(q, off); }
  __shared__ float red[2][2];
  if ((t & 63) == 0){ red[t>>6][0] = s; red[t>>6][1] = q; }
  __syncthreads();
  float S = red[0][0] + red[1][0], Q = red[0][1] + red[1][1];
  float mu = S * (1.f/384.f);
  float var = Q * (1.f/384.f) - mu*mu;
  float rs = rsqrtf(var + 1e-5f);
  int b = row / 784; int hw = row - b*784; int h = hw / 28; int w = hw - h*28;
  int hs = h - 3; if (hs < 0) hs += 28;
  int ws = w - 3; if (ws < 0) ws += 28;
  int win = b*16 + (hs/7)*4 + (ws/7);
  int n = (hs%7)*7 + (ws%7);
  u16* orow = xw + ((size_t)(win - win0)*49 + n) * 384;
  orow[t]     = f2bf((v0 - mu)*rs*g[t]     + bt[t]);
  orow[t+128] = f2bf((v1 - mu)*rs*g[t+128] + bt[t+128]);
  orow[t+256] = f2bf((v2 - mu)*rs*g[t+256] + bt[t+256]);
}

// ---- LN2 for one row chunk: x1 fp32 (d_out) rows [row0, row0+grid) -> xn bf16 local ----
__global__ __launch_bounds__(128) void ln2_kernel(const float* __restrict__ x, const float* __restrict__ g,
                                                  const float* __restrict__ bt, u16* __restrict__ xn, int row0){
  int row = row0 + blockIdx.x;
  const float* xr = x + (size_t)row * 384;
  int t = threadIdx.x;
  float v0 = xr[t], v1 = xr[t+128], v2 = xr[t+256];
  float s = v0+v1+v2;
  float q = v0*v0+v1*v1+v2*v2;
  #pragma unroll
  for (int off = 32; off; off >>= 1){ s += __shfl_down(s, off); q += __shfl_down(q, off); }
  __shared__ float red[2][2];
  if ((t & 63) == 0){ red[t>>6][0] = s; red[t>>6][1] = q; }
  __syncthreads();
  float S = red[0][0] + red[1][0], Q = red[0][1] + red[1][1];
  float mu = S * (1.f/384.f);
  float var = Q * (1.f/384.f) - mu*mu;
  float rs = rsqrtf(var + 1e-5f);
  u16* orow = xn + (size_t)blockIdx.x * 384;
  orow[t]     = f2bf((v0 - mu)*rs*g[t]     + bt[t]);
  orow[t+128] = f2bf((v1 - mu)*rs*g[t+128] + bt[t+128]);
  orow[t+256] = f2bf((v2 - mu)*rs*g[t+256] + bt[t+256]);
}

// ---- generic 128x128x32 MFMA GEMM, Bt is (N,K) bf16 ----
template<class Epi>
__global__ __launch_bounds__(256) void gemm_bt(const u16* __restrict__ A, const u16* __restrict__ Bt,
                                               int K, Epi epi){
  __shared__ __align__(16) u16 lds_a[128*40];
  __shared__ __align__(16) u16 lds_b[128*40];
  const int tid = threadIdx.x;
  const int lane = tid & 63, wid = tid >> 6;
  const int wm = wid >> 1, wn = wid & 1;
  const int quad = lane >> 4, l16 = lane & 15;
  const int m0 = blockIdx.x * 128, n0 = blockIdx.y * 128;

  f32x4 acc[4][4];
  #pragma unroll
  for (int i = 0; i < 4; i++)
    #pragma unroll
    for (int j = 0; j < 4; j++){ f32x4 z = {0.f,0.f,0.f,0.f}; acc[i][j] = z; }

  for (int k0 = 0; k0 < K; k0 += 32){
    #pragma unroll
    for (int it = 0; it < 2; it++){
      int c = tid + it*256;
      int row = c >> 2, k8 = (c & 3) << 3;
      *(uint4*)&lds_a[row*40 + k8] = *(const uint4*)&A[(size_t)(m0+row)*K + k0 + k8];
      *(uint4*)&lds_b[row*40 + k8] = *(const uint4*)&Bt[(size_t)(n0+row)*K + k0 + k8];
    }
    __syncthreads();
    bf16x8 af[4], bfr[4];
    #pragma unroll
    for (int i = 0; i < 4; i++){
      af[i]  = *(const bf16x8*)&lds_a[(wm*64 + i*16 + l16)*40 + quad*8];
      bfr[i] = *(const bf16x8*)&lds_b[(wn*64 + i*16 + l16)*40 + quad*8];
    }
    #pragma unroll
    for (int i = 0; i < 4; i++)
      #pragma unroll
      for (int j = 0; j < 4; j++)
        acc[i][j] = __builtin_amdgcn_mfma_f32_16x16x32_bf16(af[i], bfr[j], acc[i][j], 0, 0, 0);
    __syncthreads();
  }
  #pragma unroll
  for (int i = 0; i < 4; i++)
    #pragma unroll
    for (int j = 0; j < 4; j++)
      #pragma unroll
      for (int r = 0; r < 4; r++){
        int row = m0 + wm*64 + i*16 + quad*4 + r;
        int col = n0 + wn*64 + j*16 + l16;
        epi(acc[i][j][r], row, col);
      }
}

// ---- epilogues ----
struct EpiQKV {   // rows LOCAL to chunk; q/k/v chunk buffers (128 windows)
  const float* bias; u16 *q, *k, *v;
  __device__ __forceinline__ void operator()(float acc, int row, int col) const {
    float val = acc + bias[col];
    int which = col / 384; int cc = col - which*384;
    int head = cc >> 5, hd = cc & 31;
    int win = row / 49; int n = row - win*49;
    if (which == 0) val *= SCALE_;
    u16* dst = (which == 0) ? q : (which == 1) ? k : v;
    dst[((size_t)(win*12 + head)*49 + n)*32 + hd] = f2bf(val);
  }
};

struct EpiProj {  // rows local; win0 = global window offset; x1 = d_out (fp32 residual)
  const float* bias; const void* x; float* x1; const int* flags; int win0;
  __device__ __forceinline__ void operator()(float acc, int row, int col) const {
    int win = win0 + row / 49; int n = row - (row/49)*49;
    int b = win >> 4; int w16 = win & 15;
    int wh = w16 >> 2, ww = w16 & 3;
    int r = n / 7, cn = n - r*7;
    int h = wh*7 + r + 3; if (h >= 28) h -= 28;
    int w = ww*7 + cn + 3; if (w >= 28) w -= 28;
    size_t idx = ((size_t)b*784 + h*28 + w)*384 + col;
    x1[idx] = acc + bias[col] + ldf(x, idx, flags[0]);
  }
};

struct EpiFC1 {
  const float* bias; u16* hid;
  __device__ __forceinline__ void operator()(float acc, int row, int col) const {
    float x = acc + bias[col];
    float g = 0.5f * x * (1.0f + erff(x * 0.70710678118654752f));
    hid[(size_t)row*1536 + col] = f2bf(g);
  }
};

struct EpiFC2 {   // x1 == out == d_out fp32; read-then-write same idx by same lane
  const float* bias; const float* x1; float* out; size_t row_off;
  __device__ __forceinline__ void operator()(float acc, int row, int col) const {
    size_t idx = (row_off + (size_t)row)*384 + col;
    out[idx] = x1[idx] + acc + bias[col];
  }
};

// ---- attention: one block per (local window, head) ----
__global__ __launch_bounds__(256) void attn_kernel(const u16* __restrict__ q, const u16* __restrict__ kk,
                                                   const u16* __restrict__ v, const float* __restrict__ rpbf,
                                                   u16* __restrict__ o){
  __shared__ __align__(16) u16 qs[64*32];
  __shared__ __align__(16) u16 ks[64*32];
  __shared__ __align__(16) u16 vt[32*72];
  __shared__ __align__(16) u16 ps[64*72];
  __shared__ float ss[64*68];
  __shared__ float rpbs[169];

  int blk = blockIdx.x;
  int win = blk / 12, head = blk - win*12;   // local window; (win&15) == global (win&15)
  int tid = threadIdx.x, lane = tid & 63, wid = tid >> 6;
  int quad = lane >> 4, l16 = lane & 15;
  size_t base = (size_t)blk * 1568;   // 49*32

  for (int e = tid; e < 64*32; e += 256){
    qs[e] = (e < 1568) ? q[base + e]  : (u16)0;
    ks[e] = (e < 1568) ? kk[base + e] : (u16)0;
  }
  for (int e = tid; e < 32*64; e += 256){
    int d = e >> 6, j = e & 63;
    vt[d*72 + j] = (j < 49) ? v[base + j*32 + d] : (u16)0;
  }
  for (int e = tid; e < 64*72; e += 256) ps[e] = 0;
  if (tid < 169) rpbs[tid] = rpbf[tid*12 + head];
  __syncthreads();

  int i0 = wid * 16;
  bf16x8 aq = *(const bf16x8*)&qs[(i0 + l16)*32 + quad*8];
  int w16 = win & 15; int wh = w16 >> 2; int ww = w16 & 3;
  f32x4 zero = {0.f,0.f,0.f,0.f};
  #pragma unroll
  for (int nt = 0; nt < 4; nt++){
    bf16x8 bk = *(const bf16x8*)&ks[(nt*16 + l16)*32 + quad*8];
    f32x4 c = __builtin_amdgcn_mfma_f32_16x16x32_bf16(aq, bk, zero, 0, 0, 0);
    #pragma unroll
    for (int r = 0; r < 4; r++){
      int i = i0 + quad*4 + r;
      int j = nt*16 + l16;
      float val = -1e9f;
      if (i < 49 && j < 49){
        int ir = i / 7, ic = i - ir*7, jr = j / 7, jc = j - jr*7;
        int idx = (ir - jr + 6)*13 + (ic - jc + 6);
        val = c[r] + rpbs[idx];
        int gih = wh*7 + ir, giw = ww*7 + ic;
        int gjh = wh*7 + jr, gjw = ww*7 + jc;
        int li = (gih < 21 ? 0 : (gih < 25 ? 1 : 2))*3 + (giw < 21 ? 0 : (giw < 25 ? 1 : 2));
        int lj = (gjh < 21 ? 0 : (gjh < 25 ? 1 : 2))*3 + (gjw < 21 ? 0 : (gjw < 25 ? 1 : 2));
        if (li != lj) val -= 100.f;
      }
      ss[i*68 + j] = val;
    }
  }
  __syncthreads();

  for (int r = wid; r < 49; r += 4){
    float x = ss[r*68 + lane];
    float mx = x;
    #pragma unroll
    for (int off = 32; off; off >>= 1) mx = fmaxf(mx, __shfl_xor(mx, off));
    float e = expf(x - mx);
    float sum = e;
    #pragma unroll
    for (int off = 32; off; off >>= 1) sum += __shfl_xor(sum, off);
    ps[r*72 + lane] = f2bf(e / sum);
  }
  __syncthreads();

  f32x4 accO[2] = {{0.f,0.f,0.f,0.f},{0.f,0.f,0.f,0.f}};
  #pragma unroll
  for (int s = 0; s < 2; s++){
    bf16x8 ap = *(const bf16x8*)&ps[(i0 + l16)*72 + s*32 + quad*8];
    #pragma unroll
    for (int nt = 0; nt < 2; nt++){
      bf16x8 bv = *(const bf16x8*)&vt[(nt*16 + l16)*72 + s*32 + quad*8];
      accO[nt] = __builtin_amdgcn_mfma_f32_16x16x32_bf16(ap, bv, accO[nt], 0, 0, 0);
    }
  }
  #pragma unroll
  for (int nt = 0; nt < 2; nt++)
    #pragma unroll
    for (int r = 0; r < 4; r++){
      int i = i0 + quad*4 + r;
      if (i < 49){
        int col = nt*16 + l16;
        o[((size_t)win*49 + i)*384 + head*32 + col] = f2bf(accO[nt][r]);
      }
    }
}

// ---- launch ----
extern "C" void kernel_launch(void* const* d_in, const int* in_sizes, int n_in,
                              void* d_out, int out_size, void* d_ws, size_t ws_size,
                              hipStream_t stream){
  (void)n_in; (void)out_size;
  const void* x      = d_in[0];
  const void* qkv_w  = d_in[1];
  const void* qkv_b  = d_in[2];
  const void* proj_w = d_in[3];
  const void* proj_b = d_in[4];
  const void* rpb    = d_in[5];
  const void* n1g    = d_in[6];
  const void* n1b    = d_in[7];
  const void* n2g    = d_in[8];
  const void* n2b    = d_in[9];
  const void* fc1_w  = d_in[10];
  const void* fc1_b  = d_in[11];
  const void* fc2_w  = d_in[12];
  const void* fc2_b  = d_in[13];
  float* out = (float*)d_out;   // r5 evidence: output is fp32 (error 8.078 = bf16-packing signature)

  char* ws = (char*)d_ws;
  size_t off = 0;
  auto alloc = [&](size_t bytes)->void*{
    void* p = ws + off; off = (off + bytes + 255) & ~(size_t)255; return p;
  };
  int*   flags  = (int*)  alloc(14*4);
  float* prm    = (float*)alloc(7020*4);
  u16*   qkv_wt = (u16*)  alloc((size_t)384*1152*2);
  u16*   proj_wt= (u16*)  alloc((size_t)384*384*2);
  u16*   fc1_wt = (u16*)  alloc((size_t)384*1536*2);
  u16*   fc2_wt = (u16*)  alloc((size_t)1536*384*2);
  size_t fixed_end = off;
  size_t avail = (ws_size > fixed_end) ? ws_size - fixed_end : 0;

  u16* scr = (u16*)(ws + fixed_end);
  u16* xw  = scr;                                 // also attention output
  u16* qs  = scr + (size_t)ATTN_ROWS*384;
  u16* ksp = qs  + (size_t)ATTN_WINS*12*49*32;
  u16* vs  = ksp + (size_t)ATTN_WINS*12*49*32;

  int mlp_rows = 1792;                            // floor: 6.9 MB
  if ((size_t)6272*3840 <= avail) mlp_rows = 6272;
  else if ((size_t)3584*3840 <= avail) mlp_rows = 3584;
  u16* xn  = scr;
  u16* hid = scr + (size_t)mlp_rows*384;

  float* p_qkv_b = prm;
  float* p_proj_b= prm + 1152;
  float* p_fc1_b = prm + 1536;
  float* p_fc2_b = prm + 3072;
  float* p_n1g   = prm + 3456;
  float* p_n1b   = prm + 3840;
  float* p_n2g   = prm + 4224;
  float* p_n2b   = prm + 4608;
  float* p_rpb   = prm + 4992;

  Ptrs ps;
  for (int i = 0; i < 14; i++){ ps.p[i] = d_in[i]; ps.sz[i] = in_sizes[i]; }
  probe_dtypes<<<14, 64, 0, stream>>>(ps, flags);

  cvt_all<<<28, 256, 0, stream>>>(qkv_b, proj_b, fc1_b, fc2_b, n1g, n1b, n2g, n2b, rpb, flags, prm);

  transpose_k<<<(384*1152+255)/256, 256, 0, stream>>>(qkv_w,  qkv_wt, 384, 1152, flags, 1);
  transpose_k<<<(384*384 +255)/256, 256, 0, stream>>>(proj_w, proj_wt, 384, 384, flags, 3);
  transpose_k<<<(384*1536+255)/256, 256, 0, stream>>>(fc1_w,  fc1_wt, 384, 1536, flags, 10);
  transpose_k<<<(1536*384+255)/256, 256, 0, stream>>>(fc2_w,  fc2_wt, 1536, 384, flags, 12);

  // attention phase: 8 chunks of 8 batches (6272 rows, 128 windows) each
  for (int c = 0; c < 8; c++){
    int row0 = c * ATTN_ROWS, win0 = c * ATTN_WINS;
    ln1_kernel<<<ATTN_ROWS, 128, 0, stream>>>(x, p_n1g, p_n1b, xw, flags, row0, win0);
    gemm_bt<<<dim3(49, 9), 256, 0, stream>>>(xw, qkv_wt, 384, EpiQKV{p_qkv_b, qs, ksp, vs});
    attn_kernel<<<ATTN_WINS*12, 256, 0, stream>>>(qs, ksp, vs, p_rpb, xw);  // o overwrites xw
    gemm_bt<<<dim3(49, 3), 256, 0, stream>>>(xw, proj_wt, 384, EpiProj{p_proj_b, x, out, flags, win0});
  }

  // MLP phase: row chunks sized to fit ws
  for (int r0 = 0; r0 < M_ROWS; r0 += mlp_rows){
    ln2_kernel<<<mlp_rows, 128, 0, stream>>>(out, p_n2g, p_n2b, xn, r0);
    gemm_bt<<<dim3(mlp_rows/128, 12), 256, 0, stream>>>(xn, fc1_wt, 384, EpiFC1{p_fc1_b, hid});
    gemm_bt<<<dim3(mlp_rows/128, 3),  256, 0, stream>>>(hid, fc2_wt, 1536,
        EpiFC2{p_fc2_b, out, out, (size_t)r0});
  }
}

// Round 7
// 849.563 us; speedup vs baseline: 1.7491x; 1.7491x over previous
//
#include <hip/hip_runtime.h>
#include <hip/hip_bf16.h>
#include <math.h>

typedef unsigned short u16;
typedef __bf16 bf16x8 __attribute__((ext_vector_type(8)));
typedef float f32x4 __attribute__((ext_vector_type(4)));

#define M_ROWS 50176      // B*H*W = 64*28*28
#define SCALE_ 0.17677669529663687f

__device__ __forceinline__ float bf2f(u16 x){
  union { unsigned u; float f; } c; c.u = ((unsigned)x) << 16; return c.f;
}
__device__ __forceinline__ u16 f2bf(float f){
  union { float f; unsigned u; } c; c.f = f;
  unsigned u = c.u;
  u += 0x7fffu + ((u >> 16) & 1u);   // RNE
  return (u16)(u >> 16);
}
// isbf: 1 -> array is bf16, 0 -> fp32
__device__ __forceinline__ float ldf(const void* p, size_t i, int isbf){
  return isbf ? bf2f(((const u16*)p)[i]) : ((const float*)p)[i];
}

// ---- per-input dtype probe (proven r6) ----
struct Ptrs { const void* p[14]; int sz[14]; };
__global__ __launch_bounds__(64) void probe_dtypes(Ptrs ps, int* flags){
  int i = blockIdx.x;
  const unsigned* w = (const unsigned*)ps.p[i];
  int nw = ps.sz[i] >> 1;
  if (nw < 1) nw = 1;
  int stride = nw >> 6; if (!stride) stride = 1;
  int lane = threadIdx.x;
  long idx = (long)lane * stride; if (idx >= nw) idx = nw - 1;
  unsigned v = w[idx];
  unsigned L = v & 0xFFFFu;
  int lexp = (int)((L >> 7) & 0xFF);
  bool vb = (L != 0) && (lexp >= 100) && (lexp <= 141);
  bool vf = (!vb) && (v != 0);
  unsigned long long mb = __ballot(vb), mf = __ballot(vf);
  if (lane == 0) flags[i] = (__popcll(mb) >= __popcll(mf)) ? 1 : 0;
}

// ---- param conversion: all 1-D inputs -> fp32 block in ws ----
__global__ void cvt_all(const void* qkv_b, const void* proj_b, const void* fc1_b, const void* fc2_b,
                        const void* n1g, const void* n1b, const void* n2g, const void* n2b,
                        const void* rpb, const int* __restrict__ flags, float* dst){
  int i = blockIdx.x * 256 + threadIdx.x;
  if (i >= 7020) return;
  const void* src; int loc, fi;
  if      (i < 1152){ src = qkv_b; loc = i;        fi = 2; }
  else if (i < 1536){ src = proj_b; loc = i - 1152; fi = 4; }
  else if (i < 3072){ src = fc1_b; loc = i - 1536; fi = 11; }
  else if (i < 3456){ src = fc2_b; loc = i - 3072; fi = 13; }
  else if (i < 3840){ src = n1g;  loc = i - 3456; fi = 6; }
  else if (i < 4224){ src = n1b;  loc = i - 3840; fi = 7; }
  else if (i < 4608){ src = n2g;  loc = i - 4224; fi = 8; }
  else if (i < 4992){ src = n2b;  loc = i - 4608; fi = 9; }
  else              { src = rpb;  loc = i - 4992; fi = 5; }
  dst[i] = ldf(src, loc, flags[fi]);
}

// ---- weight transpose: in (K,N) either dtype -> out (N,K) bf16 ----
__global__ void transpose_k(const void* __restrict__ in, u16* __restrict__ out, int K, int N,
                            const int* __restrict__ flags, int fi){
  int tid = blockIdx.x * 256 + threadIdx.x;
  if (tid < K * N){
    int n = tid / K, k = tid - n * K;
    out[tid] = f2bf(ldf(in, (size_t)k * N + n, flags[fi]));
  }
}

// ---- LN1 + shift + window partition for rows [row0, row0+grid) ----
__global__ __launch_bounds__(128) void ln1_kernel(const void* __restrict__ x, const float* __restrict__ g,
                                                  const float* __restrict__ bt, u16* __restrict__ xw,
                                                  const int* __restrict__ flags, int row0, int win0){
  int row = row0 + blockIdx.x;
  int bf = flags[0];
  size_t base = (size_t)row * 384;
  int t = threadIdx.x;
  float v0 = ldf(x, base + t, bf), v1 = ldf(x, base + t + 128, bf), v2 = ldf(x, base + t + 256, bf);
  float s = v0+v1+v2;
  float q = v0*v0+v1*v1+v2*v2;
  #pragma unroll
  for (int off = 32; off; off >>= 1){ s += __shfl_down(s, off); q += __shfl_down(q, off); }
  __shared__ float red[2][2];
  if ((t & 63) == 0){ red[t>>6][0] = s; red[t>>6][1] = q; }
  __syncthreads();
  float S = red[0][0] + red[1][0], Q = red[0][1] + red[1][1];
  float mu = S * (1.f/384.f);
  float var = Q * (1.f/384.f) - mu*mu;
  float rs = rsqrtf(var + 1e-5f);
  int b = row / 784; int hw = row - b*784; int h = hw / 28; int w = hw - h*28;
  int hs = h - 3; if (hs < 0) hs += 28;
  int ws = w - 3; if (ws < 0) ws += 28;
  int win = b*16 + (hs/7)*4 + (ws/7);
  int n = (hs%7)*7 + (ws%7);
  u16* orow = xw + ((size_t)(win - win0)*49 + n) * 384;
  orow[t]     = f2bf((v0 - mu)*rs*g[t]     + bt[t]);
  orow[t+128] = f2bf((v1 - mu)*rs*g[t+128] + bt[t+128]);
  orow[t+256] = f2bf((v2 - mu)*rs*g[t+256] + bt[t+256]);
}

// ---- LN2: x1 fp32 (d_out) rows [row0, row0+grid) -> xn bf16 local ----
__global__ __launch_bounds__(128) void ln2_kernel(const float* __restrict__ x, const float* __restrict__ g,
                                                  const float* __restrict__ bt, u16* __restrict__ xn, int row0){
  int row = row0 + blockIdx.x;
  const float* xr = x + (size_t)row * 384;
  int t = threadIdx.x;
  float v0 = xr[t], v1 = xr[t+128], v2 = xr[t+256];
  float s = v0+v1+v2;
  float q = v0*v0+v1*v1+v2*v2;
  #pragma unroll
  for (int off = 32; off; off >>= 1){ s += __shfl_down(s, off); q += __shfl_down(q, off); }
  __shared__ float red[2][2];
  if ((t & 63) == 0){ red[t>>6][0] = s; red[t>>6][1] = q; }
  __syncthreads();
  float S = red[0][0] + red[1][0], Q = red[0][1] + red[1][1];
  float mu = S * (1.f/384.f);
  float var = Q * (1.f/384.f) - mu*mu;
  float rs = rsqrtf(var + 1e-5f);
  u16* orow = xn + (size_t)blockIdx.x * 384;
  orow[t]     = f2bf((v0 - mu)*rs*g[t]     + bt[t]);
  orow[t+128] = f2bf((v1 - mu)*rs*g[t+128] + bt[t+128]);
  orow[t+256] = f2bf((v2 - mu)*rs*g[t+256] + bt[t+256]);
}

// ---- generic 128x128x32 MFMA GEMM, Bt is (N,K) bf16 ----
template<class Epi>
__global__ __launch_bounds__(256) void gemm_bt(const u16* __restrict__ A, const u16* __restrict__ Bt,
                                               int K, Epi epi){
  __shared__ __align__(16) u16 lds_a[128*40];
  __shared__ __align__(16) u16 lds_b[128*40];
  const int tid = threadIdx.x;
  const int lane = tid & 63, wid = tid >> 6;
  const int wm = wid >> 1, wn = wid & 1;
  const int quad = lane >> 4, l16 = lane & 15;
  const int m0 = blockIdx.x * 128, n0 = blockIdx.y * 128;

  f32x4 acc[4][4];
  #pragma unroll
  for (int i = 0; i < 4; i++)
    #pragma unroll
    for (int j = 0; j < 4; j++){ f32x4 z = {0.f,0.f,0.f,0.f}; acc[i][j] = z; }

  for (int k0 = 0; k0 < K; k0 += 32){
    #pragma unroll
    for (int it = 0; it < 2; it++){
      int c = tid + it*256;
      int row = c >> 2, k8 = (c & 3) << 3;
      *(uint4*)&lds_a[row*40 + k8] = *(const uint4*)&A[(size_t)(m0+row)*K + k0 + k8];
      *(uint4*)&lds_b[row*40 + k8] = *(const uint4*)&Bt[(size_t)(n0+row)*K + k0 + k8];
    }
    __syncthreads();
    bf16x8 af[4], bfr[4];
    #pragma unroll
    for (int i = 0; i < 4; i++){
      af[i]  = *(const bf16x8*)&lds_a[(wm*64 + i*16 + l16)*40 + quad*8];
      bfr[i] = *(const bf16x8*)&lds_b[(wn*64 + i*16 + l16)*40 + quad*8];
    }
    #pragma unroll
    for (int i = 0; i < 4; i++)
      #pragma unroll
      for (int j = 0; j < 4; j++)
        acc[i][j] = __builtin_amdgcn_mfma_f32_16x16x32_bf16(af[i], bfr[j], acc[i][j], 0, 0, 0);
    __syncthreads();
  }
  #pragma unroll
  for (int i = 0; i < 4; i++)
    #pragma unroll
    for (int j = 0; j < 4; j++)
      #pragma unroll
      for (int r = 0; r < 4; r++){
        int row = m0 + wm*64 + i*16 + quad*4 + r;
        int col = n0 + wn*64 + j*16 + l16;
        epi(acc[i][j][r], row, col);
      }
}

// ---- epilogues ----
struct EpiQKV {   // rows LOCAL to chunk; q/k/v chunk buffers
  const float* bias; u16 *q, *k, *v;
  __device__ __forceinline__ void operator()(float acc, int row, int col) const {
    float val = acc + bias[col];
    int which = col / 384; int cc = col - which*384;
    int head = cc >> 5, hd = cc & 31;
    int win = row / 49; int n = row - win*49;
    if (which == 0) val *= SCALE_;
    u16* dst = (which == 0) ? q : (which == 1) ? k : v;
    dst[((size_t)(win*12 + head)*49 + n)*32 + hd] = f2bf(val);
  }
};

struct EpiProj {  // rows local; win0 = global window offset; x1 = d_out (fp32 residual)
  const float* bias; const void* x; float* x1; const int* flags; int win0;
  __device__ __forceinline__ void operator()(float acc, int row, int col) const {
    int win = win0 + row / 49; int n = row - (row/49)*49;
    int b = win >> 4; int w16 = win & 15;
    int wh = w16 >> 2, ww = w16 & 3;
    int r = n / 7, cn = n - r*7;
    int h = wh*7 + r + 3; if (h >= 28) h -= 28;
    int w = ww*7 + cn + 3; if (w >= 28) w -= 28;
    size_t idx = ((size_t)b*784 + h*28 + w)*384 + col;
    x1[idx] = acc + bias[col] + ldf(x, idx, flags[0]);
  }
};

struct EpiFC1 {
  const float* bias; u16* hid;
  __device__ __forceinline__ void operator()(float acc, int row, int col) const {
    float x = acc + bias[col];
    float g = 0.5f * x * (1.0f + erff(x * 0.70710678118654752f));
    hid[(size_t)row*1536 + col] = f2bf(g);
  }
};

struct EpiFC2 {   // x1 == out == d_out fp32; same lane reads+writes idx
  const float* bias; const float* x1; float* out; size_t row_off;
  __device__ __forceinline__ void operator()(float acc, int row, int col) const {
    size_t idx = (row_off + (size_t)row)*384 + col;
    out[idx] = x1[idx] + acc + bias[col];
  }
};

// ---- attention: one block per (local window, head) ----
__global__ __launch_bounds__(256) void attn_kernel(const u16* __restrict__ q, const u16* __restrict__ kk,
                                                   const u16* __restrict__ v, const float* __restrict__ rpbf,
                                                   u16* __restrict__ o){
  __shared__ __align__(16) u16 qs[64*32];
  __shared__ __align__(16) u16 ks[64*32];
  __shared__ __align__(16) u16 vt[32*72];
  __shared__ __align__(16) u16 ps[64*72];
  __shared__ float ss[64*68];
  __shared__ float rpbs[169];

  int blk = blockIdx.x;
  int win = blk / 12, head = blk - win*12;   // local window; (win&15) == global (win&15)
  int tid = threadIdx.x, lane = tid & 63, wid = tid >> 6;
  int quad = lane >> 4, l16 = lane & 15;
  size_t base = (size_t)blk * 1568;   // 49*32

  for (int e = tid; e < 64*32; e += 256){
    qs[e] = (e < 1568) ? q[base + e]  : (u16)0;
    ks[e] = (e < 1568) ? kk[base + e] : (u16)0;
  }
  for (int e = tid; e < 32*64; e += 256){
    int d = e >> 6, j = e & 63;
    vt[d*72 + j] = (j < 49) ? v[base + j*32 + d] : (u16)0;
  }
  for (int e = tid; e < 64*72; e += 256) ps[e] = 0;
  if (tid < 169) rpbs[tid] = rpbf[tid*12 + head];
  __syncthreads();

  int i0 = wid * 16;
  bf16x8 aq = *(const bf16x8*)&qs[(i0 + l16)*32 + quad*8];
  int w16 = win & 15; int wh = w16 >> 2; int ww = w16 & 3;
  f32x4 zero = {0.f,0.f,0.f,0.f};
  #pragma unroll
  for (int nt = 0; nt < 4; nt++){
    bf16x8 bk = *(const bf16x8*)&ks[(nt*16 + l16)*32 + quad*8];
    f32x4 c = __builtin_amdgcn_mfma_f32_16x16x32_bf16(aq, bk, zero, 0, 0, 0);
    #pragma unroll
    for (int r = 0; r < 4; r++){
      int i = i0 + quad*4 + r;
      int j = nt*16 + l16;
      float val = -1e9f;
      if (i < 49 && j < 49){
        int ir = i / 7, ic = i - ir*7, jr = j / 7, jc = j - jr*7;
        int idx = (ir - jr + 6)*13 + (ic - jc + 6);
        val = c[r] + rpbs[idx];
        int gih = wh*7 + ir, giw = ww*7 + ic;
        int gjh = wh*7 + jr, gjw = ww*7 + jc;
        int li = (gih < 21 ? 0 : (gih < 25 ? 1 : 2))*3 + (giw < 21 ? 0 : (giw < 25 ? 1 : 2));
        int lj = (gjh < 21 ? 0 : (gjh < 25 ? 1 : 2))*3 + (gjw < 21 ? 0 : (gjw < 25 ? 1 : 2));
        if (li != lj) val -= 100.f;
      }
      ss[i*68 + j] = val;
    }
  }
  __syncthreads();

  for (int r = wid; r < 49; r += 4){
    float x = ss[r*68 + lane];
    float mx = x;
    #pragma unroll
    for (int off = 32; off; off >>= 1) mx = fmaxf(mx, __shfl_xor(mx, off));
    float e = expf(x - mx);
    float sum = e;
    #pragma unroll
    for (int off = 32; off; off >>= 1) sum += __shfl_xor(sum, off);
    ps[r*72 + lane] = f2bf(e / sum);
  }
  __syncthreads();

  f32x4 accO[2] = {{0.f,0.f,0.f,0.f},{0.f,0.f,0.f,0.f}};
  #pragma unroll
  for (int s = 0; s < 2; s++){
    bf16x8 ap = *(const bf16x8*)&ps[(i0 + l16)*72 + s*32 + quad*8];
    #pragma unroll
    for (int nt = 0; nt < 2; nt++){
      bf16x8 bv = *(const bf16x8*)&vt[(nt*16 + l16)*72 + s*32 + quad*8];
      accO[nt] = __builtin_amdgcn_mfma_f32_16x16x32_bf16(ap, bv, accO[nt], 0, 0, 0);
    }
  }
  #pragma unroll
  for (int nt = 0; nt < 2; nt++)
    #pragma unroll
    for (int r = 0; r < 4; r++){
      int i = i0 + quad*4 + r;
      if (i < 49){
        int col = nt*16 + l16;
        o[((size_t)win*49 + i)*384 + head*32 + col] = f2bf(accO[nt][r]);
      }
    }
}

// ---- launch ----
extern "C" void kernel_launch(void* const* d_in, const int* in_sizes, int n_in,
                              void* d_out, int out_size, void* d_ws, size_t ws_size,
                              hipStream_t stream){
  (void)n_in; (void)out_size;
  const void* x      = d_in[0];
  const void* qkv_w  = d_in[1];
  const void* qkv_b  = d_in[2];
  const void* proj_w = d_in[3];
  const void* proj_b = d_in[4];
  const void* rpb    = d_in[5];
  const void* n1g    = d_in[6];
  const void* n1b    = d_in[7];
  const void* n2g    = d_in[8];
  const void* n2b    = d_in[9];
  const void* fc1_w  = d_in[10];
  const void* fc1_b  = d_in[11];
  const void* fc2_w  = d_in[12];
  const void* fc2_b  = d_in[13];
  float* out = (float*)d_out;   // fp32 output (verified r6)

  char* ws = (char*)d_ws;
  size_t off = 0;
  auto alloc = [&](size_t bytes)->void*{
    void* p = ws + off; off = (off + bytes + 255) & ~(size_t)255; return p;
  };
  int*   flags  = (int*)  alloc(14*4);
  float* prm    = (float*)alloc(7020*4);
  u16*   qkv_wt = (u16*)  alloc((size_t)384*1152*2);
  u16*   proj_wt= (u16*)  alloc((size_t)384*384*2);
  u16*   fc1_wt = (u16*)  alloc((size_t)384*1536*2);
  u16*   fc2_wt = (u16*)  alloc((size_t)1536*384*2);
  size_t fixed_end = off;
  size_t avail = (ws_size > fixed_end) ? ws_size - fixed_end : 0;

  // adaptive chunk sizes: prefer full-M single launches (r6 post-mortem:
  // 147-block grids ran at 5.7% occupancy; full-M grids are 8x bigger)
  int attn_wins = 128;                             // per-win scratch: 150528 B
  if      ((size_t)1024*150528 <= avail) attn_wins = 1024;
  else if ((size_t)512 *150528 <= avail) attn_wins = 512;
  else if ((size_t)256 *150528 <= avail) attn_wins = 256;

  int mlp_rows = 1792;                             // per-row scratch: 3840 B
  if      ((size_t)50176*3840 <= avail) mlp_rows = 50176;
  else if ((size_t)25088*3840 <= avail) mlp_rows = 25088;
  else if ((size_t)12544*3840 <= avail) mlp_rows = 12544;
  else if ((size_t)6272 *3840 <= avail) mlp_rows = 6272;

  u16* scr = (u16*)(ws + fixed_end);
  u16* xw  = scr;                                  // attn chunk input; also attention output
  u16* qs  = scr + (size_t)attn_wins*49*384;
  u16* ksp = qs  + (size_t)attn_wins*12*49*32;
  u16* vs  = ksp + (size_t)attn_wins*12*49*32;
  u16* xn  = scr;
  u16* hid = scr + (size_t)mlp_rows*384;

  float* p_qkv_b = prm;
  float* p_proj_b= prm + 1152;
  float* p_fc1_b = prm + 1536;
  float* p_fc2_b = prm + 3072;
  float* p_n1g   = prm + 3456;
  float* p_n1b   = prm + 3840;
  float* p_n2g   = prm + 4224;
  float* p_n2b   = prm + 4608;
  float* p_rpb   = prm + 4992;

  Ptrs ps;
  for (int i = 0; i < 14; i++){ ps.p[i] = d_in[i]; ps.sz[i] = in_sizes[i]; }
  probe_dtypes<<<14, 64, 0, stream>>>(ps, flags);

  cvt_all<<<28, 256, 0, stream>>>(qkv_b, proj_b, fc1_b, fc2_b, n1g, n1b, n2g, n2b, rpb, flags, prm);

  transpose_k<<<(384*1152+255)/256, 256, 0, stream>>>(qkv_w,  qkv_wt, 384, 1152, flags, 1);
  transpose_k<<<(384*384 +255)/256, 256, 0, stream>>>(proj_w, proj_wt, 384, 384, flags, 3);
  transpose_k<<<(384*1536+255)/256, 256, 0, stream>>>(fc1_w,  fc1_wt, 384, 1536, flags, 10);
  transpose_k<<<(1536*384+255)/256, 256, 0, stream>>>(fc2_w,  fc2_wt, 1536, 384, flags, 12);

  // attention phase
  int nch = 1024 / attn_wins;
  for (int c = 0; c < nch; c++){
    int win0 = c * attn_wins, row0 = win0 * 49;
    int mrows = attn_wins * 49;
    ln1_kernel<<<mrows, 128, 0, stream>>>(x, p_n1g, p_n1b, xw, flags, row0, win0);
    gemm_bt<<<dim3(mrows/128, 9), 256, 0, stream>>>(xw, qkv_wt, 384, EpiQKV{p_qkv_b, qs, ksp, vs});
    attn_kernel<<<attn_wins*12, 256, 0, stream>>>(qs, ksp, vs, p_rpb, xw);  // o overwrites xw
    gemm_bt<<<dim3(mrows/128, 3), 256, 0, stream>>>(xw, proj_wt, 384, EpiProj{p_proj_b, x, out, flags, win0});
  }

  // MLP phase
  for (int r0 = 0; r0 < M_ROWS; r0 += mlp_rows){
    ln2_kernel<<<mlp_rows, 128, 0, stream>>>(out, p_n2g, p_n2b, xn, r0);
    gemm_bt<<<dim3(mlp_rows/128, 12), 256, 0, stream>>>(xn, fc1_wt, 384, EpiFC1{p_fc1_b, hid});
    gemm_bt<<<dim3(mlp_rows/128, 3),  256, 0, stream>>>(hid, fc2_wt, 1536,
        EpiFC2{p_fc2_b, out, out, (size_t)r0});
  }
}

// Round 8
// 811.180 us; speedup vs baseline: 1.8318x; 1.0473x over previous
//
#include <hip/hip_runtime.h>
#include <hip/hip_bf16.h>
#include <math.h>

typedef unsigned short u16;
typedef __bf16 bf16x8 __attribute__((ext_vector_type(8)));
typedef float f32x4 __attribute__((ext_vector_type(4)));

#define M_ROWS 50176      // B*H*W = 64*28*28
#define SCALE_ 0.17677669529663687f

__device__ __forceinline__ float bf2f(u16 x){
  union { unsigned u; float f; } c; c.u = ((unsigned)x) << 16; return c.f;
}
__device__ __forceinline__ u16 f2bf(float f){
  union { float f; unsigned u; } c; c.f = f;
  unsigned u = c.u;
  u += 0x7fffu + ((u >> 16) & 1u);   // RNE
  return (u16)(u >> 16);
}
// isbf: 1 -> array is bf16, 0 -> fp32
__device__ __forceinline__ float ldf(const void* p, size_t i, int isbf){
  return isbf ? bf2f(((const u16*)p)[i]) : ((const float*)p)[i];
}

// ---- per-input dtype probe (proven r6) ----
struct Ptrs { const void* p[14]; int sz[14]; };
__global__ __launch_bounds__(64) void probe_dtypes(Ptrs ps, int* flags){
  int i = blockIdx.x;
  const unsigned* w = (const unsigned*)ps.p[i];
  int nw = ps.sz[i] >> 1;
  if (nw < 1) nw = 1;
  int stride = nw >> 6; if (!stride) stride = 1;
  int lane = threadIdx.x;
  long idx = (long)lane * stride; if (idx >= nw) idx = nw - 1;
  unsigned v = w[idx];
  unsigned L = v & 0xFFFFu;
  int lexp = (int)((L >> 7) & 0xFF);
  bool vb = (L != 0) && (lexp >= 100) && (lexp <= 141);
  bool vf = (!vb) && (v != 0);
  unsigned long long mb = __ballot(vb), mf = __ballot(vf);
  if (lane == 0) flags[i] = (__popcll(mb) >= __popcll(mf)) ? 1 : 0;
}

// ---- param conversion: all 1-D inputs -> fp32 block in ws ----
__global__ void cvt_all(const void* qkv_b, const void* proj_b, const void* fc1_b, const void* fc2_b,
                        const void* n1g, const void* n1b, const void* n2g, const void* n2b,
                        const void* rpb, const int* __restrict__ flags, float* dst){
  int i = blockIdx.x * 256 + threadIdx.x;
  if (i >= 7020) return;
  const void* src; int loc, fi;
  if      (i < 1152){ src = qkv_b; loc = i;        fi = 2; }
  else if (i < 1536){ src = proj_b; loc = i - 1152; fi = 4; }
  else if (i < 3072){ src = fc1_b; loc = i - 1536; fi = 11; }
  else if (i < 3456){ src = fc2_b; loc = i - 3072; fi = 13; }
  else if (i < 3840){ src = n1g;  loc = i - 3456; fi = 6; }
  else if (i < 4224){ src = n1b;  loc = i - 3840; fi = 7; }
  else if (i < 4608){ src = n2g;  loc = i - 4224; fi = 8; }
  else if (i < 4992){ src = n2b;  loc = i - 4608; fi = 9; }
  else              { src = rpb;  loc = i - 4992; fi = 5; }
  dst[i] = ldf(src, loc, flags[fi]);
}

// ---- weight transpose: in (K,N) either dtype -> out (N,K) bf16 ----
__global__ void transpose_k(const void* __restrict__ in, u16* __restrict__ out, int K, int N,
                            const int* __restrict__ flags, int fi){
  int tid = blockIdx.x * 256 + threadIdx.x;
  if (tid < K * N){
    int n = tid / K, k = tid - n * K;
    out[tid] = f2bf(ldf(in, (size_t)k * N + n, flags[fi]));
  }
}

// ---- bias+mask table: bm[wtype(4)][head(12)][64][64] bf16 ----
// rows>=49 -> 0 ; cols>=49 -> -1e9 ; else rpb bias + (-100 if cross-region)
__global__ __launch_bounds__(256) void build_bm(const float* __restrict__ rpbf, u16* __restrict__ bm_g){
  int wt = blockIdx.x / 12, head = blockIdx.x - wt*12;
  u16* dst = bm_g + (size_t)blockIdx.x * 4096;
  bool he = (wt & 2), we = (wt & 1);
  for (int e = threadIdx.x; e < 4096; e += 256){
    int i = e >> 6, j = e & 63;
    float val;
    if (i >= 49) val = 0.f;
    else if (j >= 49) val = -1e9f;
    else {
      int ir = i/7, ic = i - ir*7, jr = j/7, jc = j - jr*7;
      int idx = (ir - jr + 6)*13 + (ic - jc + 6);
      val = rpbf[idx*12 + head];
      int li = (he ? (ir < 4 ? 1 : 2) : 0)*3 + (we ? (ic < 4 ? 1 : 2) : 0);
      int lj = (he ? (jr < 4 ? 1 : 2) : 0)*3 + (we ? (jc < 4 ? 1 : 2) : 0);
      if (li != lj) val -= 100.f;
    }
    dst[e] = f2bf(val);
  }
}

// ---- LN1 + shift + window partition for rows [row0, row0+grid) ----
__global__ __launch_bounds__(128) void ln1_kernel(const void* __restrict__ x, const float* __restrict__ g,
                                                  const float* __restrict__ bt, u16* __restrict__ xw,
                                                  const int* __restrict__ flags, int row0, int win0){
  int row = row0 + blockIdx.x;
  int bf = flags[0];
  size_t base = (size_t)row * 384;
  int t = threadIdx.x;
  float v0 = ldf(x, base + t, bf), v1 = ldf(x, base + t + 128, bf), v2 = ldf(x, base + t + 256, bf);
  float s = v0+v1+v2;
  float q = v0*v0+v1*v1+v2*v2;
  #pragma unroll
  for (int off = 32; off; off >>= 1){ s += __shfl_down(s, off); q += __shfl_down(q, off); }
  __shared__ float red[2][2];
  if ((t & 63) == 0){ red[t>>6][0] = s; red[t>>6][1] = q; }
  __syncthreads();
  float S = red[0][0] + red[1][0], Q = red[0][1] + red[1][1];
  float mu = S * (1.f/384.f);
  float var = Q * (1.f/384.f) - mu*mu;
  float rs = rsqrtf(var + 1e-5f);
  int b = row / 784; int hw = row - b*784; int h = hw / 28; int w = hw - h*28;
  int hs = h - 3; if (hs < 0) hs += 28;
  int ws = w - 3; if (ws < 0) ws += 28;
  int win = b*16 + (hs/7)*4 + (ws/7);
  int n = (hs%7)*7 + (ws%7);
  u16* orow = xw + ((size_t)(win - win0)*49 + n) * 384;
  orow[t]     = f2bf((v0 - mu)*rs*g[t]     + bt[t]);
  orow[t+128] = f2bf((v1 - mu)*rs*g[t+128] + bt[t+128]);
  orow[t+256] = f2bf((v2 - mu)*rs*g[t+256] + bt[t+256]);
}

// ---- LN2: x1 fp32 (d_out) rows [row0, row0+grid) -> xn bf16 local ----
__global__ __launch_bounds__(128) void ln2_kernel(const float* __restrict__ x, const float* __restrict__ g,
                                                  const float* __restrict__ bt, u16* __restrict__ xn, int row0){
  int row = row0 + blockIdx.x;
  const float* xr = x + (size_t)row * 384;
  int t = threadIdx.x;
  float v0 = xr[t], v1 = xr[t+128], v2 = xr[t+256];
  float s = v0+v1+v2;
  float q = v0*v0+v1*v1+v2*v2;
  #pragma unroll
  for (int off = 32; off; off >>= 1){ s += __shfl_down(s, off); q += __shfl_down(q, off); }
  __shared__ float red[2][2];
  if ((t & 63) == 0){ red[t>>6][0] = s; red[t>>6][1] = q; }
  __syncthreads();
  float S = red[0][0] + red[1][0], Q = red[0][1] + red[1][1];
  float mu = S * (1.f/384.f);
  float var = Q * (1.f/384.f) - mu*mu;
  float rs = rsqrtf(var + 1e-5f);
  u16* orow = xn + (size_t)blockIdx.x * 384;
  orow[t]     = f2bf((v0 - mu)*rs*g[t]     + bt[t]);
  orow[t+128] = f2bf((v1 - mu)*rs*g[t+128] + bt[t+128]);
  orow[t+256] = f2bf((v2 - mu)*rs*g[t+256] + bt[t+256]);
}

// ---- generic 128x128x32 MFMA GEMM, Bt is (N,K) bf16 ----
template<class Epi>
__global__ __launch_bounds__(256) void gemm_bt(const u16* __restrict__ A, const u16* __restrict__ Bt,
                                               int K, Epi epi){
  __shared__ __align__(16) u16 lds_a[128*40];
  __shared__ __align__(16) u16 lds_b[128*40];
  const int tid = threadIdx.x;
  const int lane = tid & 63, wid = tid >> 6;
  const int wm = wid >> 1, wn = wid & 1;
  const int quad = lane >> 4, l16 = lane & 15;
  const int m0 = blockIdx.x * 128, n0 = blockIdx.y * 128;

  f32x4 acc[4][4];
  #pragma unroll
  for (int i = 0; i < 4; i++)
    #pragma unroll
    for (int j = 0; j < 4; j++){ f32x4 z = {0.f,0.f,0.f,0.f}; acc[i][j] = z; }

  for (int k0 = 0; k0 < K; k0 += 32){
    #pragma unroll
    for (int it = 0; it < 2; it++){
      int c = tid + it*256;
      int row = c >> 2, k8 = (c & 3) << 3;
      *(uint4*)&lds_a[row*40 + k8] = *(const uint4*)&A[(size_t)(m0+row)*K + k0 + k8];
      *(uint4*)&lds_b[row*40 + k8] = *(const uint4*)&Bt[(size_t)(n0+row)*K + k0 + k8];
    }
    __syncthreads();
    bf16x8 af[4], bfr[4];
    #pragma unroll
    for (int i = 0; i < 4; i++){
      af[i]  = *(const bf16x8*)&lds_a[(wm*64 + i*16 + l16)*40 + quad*8];
      bfr[i] = *(const bf16x8*)&lds_b[(wn*64 + i*16 + l16)*40 + quad*8];
    }
    #pragma unroll
    for (int i = 0; i < 4; i++)
      #pragma unroll
      for (int j = 0; j < 4; j++)
        acc[i][j] = __builtin_amdgcn_mfma_f32_16x16x32_bf16(af[i], bfr[j], acc[i][j], 0, 0, 0);
    __syncthreads();
  }
  #pragma unroll
  for (int i = 0; i < 4; i++)
    #pragma unroll
    for (int j = 0; j < 4; j++)
      #pragma unroll
      for (int r = 0; r < 4; r++){
        int row = m0 + wm*64 + i*16 + quad*4 + r;
        int col = n0 + wn*64 + j*16 + l16;
        epi(acc[i][j][r], row, col);
      }
}

// ---- epilogues ----
struct EpiQKV {   // rows LOCAL to chunk; v stored TRANSPOSED+padded: [wh][hd(32)][64]
  const float* bias; u16 *q, *k, *vt;
  __device__ __forceinline__ void operator()(float acc, int row, int col) const {
    float val = acc + bias[col];
    int which = col / 384; int cc = col - which*384;
    int head = cc >> 5, hd = cc & 31;
    int win = row / 49; int n = row - win*49;
    if (which == 0){
      q[((size_t)(win*12 + head)*49 + n)*32 + hd] = f2bf(val * SCALE_);
    } else if (which == 1){
      k[((size_t)(win*12 + head)*49 + n)*32 + hd] = f2bf(val);
    } else {
      vt[((size_t)(win*12 + head)*32 + hd)*64 + n] = f2bf(val);
    }
  }
};

struct EpiProj {  // rows local; win0 = global window offset; x1 = d_out (fp32 residual)
  const float* bias; const void* x; float* x1; const int* flags; int win0;
  __device__ __forceinline__ void operator()(float acc, int row, int col) const {
    int win = win0 + row / 49; int n = row - (row/49)*49;
    int b = win >> 4; int w16 = win & 15;
    int wh = w16 >> 2, ww = w16 & 3;
    int r = n / 7, cn = n - r*7;
    int h = wh*7 + r + 3; if (h >= 28) h -= 28;
    int w = ww*7 + cn + 3; if (w >= 28) w -= 28;
    size_t idx = ((size_t)b*784 + h*28 + w)*384 + col;
    x1[idx] = acc + bias[col] + ldf(x, idx, flags[0]);
  }
};

struct EpiFC1 {
  const float* bias; u16* hid;
  __device__ __forceinline__ void operator()(float acc, int row, int col) const {
    float x = acc + bias[col];
    float g = 0.5f * x * (1.0f + erff(x * 0.70710678118654752f));
    hid[(size_t)row*1536 + col] = f2bf(g);
  }
};

struct EpiFC2 {   // x1 == out == d_out fp32; same lane reads+writes idx
  const float* bias; const float* x1; float* out; size_t row_off;
  __device__ __forceinline__ void operator()(float acc, int row, int col) const {
    size_t idx = (row_off + (size_t)row)*384 + col;
    out[idx] = x1[idx] + acc + bias[col];
  }
};

// ---- attention v2: one block per (local window, head) ----
// Frags direct from global; bias+mask from precomputed table; in-register softmax.
// LDS = ps(9.2KB) + bm slice(9.2KB); single barrier.
__global__ __launch_bounds__(256) void attn_kernel(const u16* __restrict__ q, const u16* __restrict__ kk,
                                                   const u16* __restrict__ vt_g, const u16* __restrict__ bm_g,
                                                   u16* __restrict__ o){
  __shared__ __align__(16) u16 ps[64*72];
  __shared__ __align__(16) u16 bms[64*72];
  int blk = blockIdx.x;
  int win = blk / 12, head = blk - win*12;
  int tid = threadIdx.x, lane = tid & 63, wid = tid >> 6;
  int quad = lane >> 4, l16 = lane & 15;
  size_t base = (size_t)blk * 1568;   // q/k: 49*32 per (win,head)

  // stage bm slice (wtype, head): 64x64 u16 -> LDS stride 72 (16B-aligned rows)
  int w16 = win & 15;
  int wt = (((w16 >> 2) == 3) ? 2 : 0) + (((w16 & 3) == 3) ? 1 : 0);
  const u16* bsrc = bm_g + (size_t)(wt*12 + head) * 4096;
  #pragma unroll
  for (int it = 0; it < 2; it++){
    int e = tid + it*256;              // 512 x 16B chunks
    int row = e >> 3, c8 = (e & 7) << 3;
    *(uint4*)&bms[row*72 + c8] = *(const uint4*)&bsrc[row*64 + c8];
  }

  // S = Q K^T via direct-global fragments (rows 49..63 overread neighbor data: finite)
  int i0 = wid * 16;
  bf16x8 aq = *(const bf16x8*)&q[base + (size_t)(i0 + l16)*32 + quad*8];
  f32x4 zero = {0.f,0.f,0.f,0.f};
  f32x4 c[4];
  #pragma unroll
  for (int nt = 0; nt < 4; nt++){
    bf16x8 bk = *(const bf16x8*)&kk[base + (size_t)(nt*16 + l16)*32 + quad*8];
    c[nt] = __builtin_amdgcn_mfma_f32_16x16x32_bf16(aq, bk, zero, 0, 0, 0);
  }
  __syncthreads();   // bms ready

  // in-register softmax: row i lives in 16 lanes (same quad) x 4 regs (nt)
  #pragma unroll
  for (int r = 0; r < 4; r++){
    int i = i0 + quad*4 + r;
    float v0 = c[0][r] + bf2f(bms[i*72 +      l16]);
    float v1 = c[1][r] + bf2f(bms[i*72 + 16 + l16]);
    float v2 = c[2][r] + bf2f(bms[i*72 + 32 + l16]);
    float v3 = c[3][r] + bf2f(bms[i*72 + 48 + l16]);
    float m = fmaxf(fmaxf(v0, v1), fmaxf(v2, v3));
    #pragma unroll
    for (int off = 1; off < 16; off <<= 1) m = fmaxf(m, __shfl_xor(m, off));
    float e0 = __expf(v0 - m), e1 = __expf(v1 - m), e2 = __expf(v2 - m), e3 = __expf(v3 - m);
    float s = e0 + e1 + e2 + e3;
    #pragma unroll
    for (int off = 1; off < 16; off <<= 1) s += __shfl_xor(s, off);
    float inv = 1.f / s;
    ps[i*72 +      l16] = f2bf(e0 * inv);
    ps[i*72 + 16 + l16] = f2bf(e1 * inv);
    ps[i*72 + 32 + l16] = f2bf(e2 * inv);
    ps[i*72 + 48 + l16] = f2bf(e3 * inv);
  }

  // O = P V : A-frag rows are the rows this wave just wrote (same-wave LDS order, no barrier)
  size_t vbase = (size_t)blk * 2048;   // vt: 32x64 per (win,head), cols>=49 zeroed by memset
  f32x4 accO[2] = {{0.f,0.f,0.f,0.f},{0.f,0.f,0.f,0.f}};
  #pragma unroll
  for (int s2 = 0; s2 < 2; s2++){
    bf16x8 ap = *(const bf16x8*)&ps[(i0 + l16)*72 + s2*32 + quad*8];
    #pragma unroll
    for (int nt = 0; nt < 2; nt++){
      bf16x8 bv = *(const bf16x8*)&vt_g[vbase + (size_t)(nt*16 + l16)*64 + s2*32 + quad*8];
      accO[nt] = __builtin_amdgcn_mfma_f32_16x16x32_bf16(ap, bv, accO[nt], 0, 0, 0);
    }
  }
  #pragma unroll
  for (int nt = 0; nt < 2; nt++)
    #pragma unroll
    for (int r = 0; r < 4; r++){
      int i = i0 + quad*4 + r;
      if (i < 49)
        o[((size_t)win*49 + i)*384 + head*32 + nt*16 + l16] = f2bf(accO[nt][r]);
    }
}

// ---- launch ----
extern "C" void kernel_launch(void* const* d_in, const int* in_sizes, int n_in,
                              void* d_out, int out_size, void* d_ws, size_t ws_size,
                              hipStream_t stream){
  (void)n_in; (void)out_size;
  const void* x      = d_in[0];
  const void* qkv_w  = d_in[1];
  const void* qkv_b  = d_in[2];
  const void* proj_w = d_in[3];
  const void* proj_b = d_in[4];
  const void* rpb    = d_in[5];
  const void* n1g    = d_in[6];
  const void* n1b    = d_in[7];
  const void* n2g    = d_in[8];
  const void* n2b    = d_in[9];
  const void* fc1_w  = d_in[10];
  const void* fc1_b  = d_in[11];
  const void* fc2_w  = d_in[12];
  const void* fc2_b  = d_in[13];
  float* out = (float*)d_out;   // fp32 output (verified r6)

  char* ws = (char*)d_ws;
  size_t off = 0;
  auto alloc = [&](size_t bytes)->void*{
    void* p = ws + off; off = (off + bytes + 255) & ~(size_t)255; return p;
  };
  int*   flags  = (int*)  alloc(14*4);
  float* prm    = (float*)alloc(7020*4);
  u16*   bm_g   = (u16*)  alloc((size_t)48*4096*2);          // 393 KB bias+mask table
  u16*   qkv_wt = (u16*)  alloc((size_t)384*1152*2);
  u16*   proj_wt= (u16*)  alloc((size_t)384*384*2);
  u16*   fc1_wt = (u16*)  alloc((size_t)384*1536*2);
  u16*   fc2_wt = (u16*)  alloc((size_t)1536*384*2);
  size_t fixed_end = off;
  size_t avail = (ws_size > fixed_end) ? ws_size - fixed_end : 0;

  // per-window attn scratch: xw 37632 + q 37632 + k 37632 + vt(padded) 49152 = 162048 B
  int attn_wins = 128;
  if      ((size_t)1024*162048 <= avail) attn_wins = 1024;
  else if ((size_t)512 *162048 <= avail) attn_wins = 512;
  else if ((size_t)256 *162048 <= avail) attn_wins = 256;

  int mlp_rows = 1792;                             // per-row scratch: 3840 B
  if      ((size_t)50176*3840 <= avail) mlp_rows = 50176;
  else if ((size_t)25088*3840 <= avail) mlp_rows = 25088;
  else if ((size_t)12544*3840 <= avail) mlp_rows = 12544;
  else if ((size_t)6272 *3840 <= avail) mlp_rows = 6272;

  u16* scr = (u16*)(ws + fixed_end);
  u16* xw  = scr;                                  // attn chunk input; also attention output
  u16* qs  = scr + (size_t)attn_wins*49*384;
  u16* ksp = qs  + (size_t)attn_wins*12*49*32;
  u16* vts = ksp + (size_t)attn_wins*12*49*32;     // transposed+padded V
  u16* xn  = scr;
  u16* hid = scr + (size_t)mlp_rows*384;

  float* p_qkv_b = prm;
  float* p_proj_b= prm + 1152;
  float* p_fc1_b = prm + 1536;
  float* p_fc2_b = prm + 3072;
  float* p_n1g   = prm + 3456;
  float* p_n1b   = prm + 3840;
  float* p_n2g   = prm + 4224;
  float* p_n2b   = prm + 4608;
  float* p_rpb   = prm + 4992;

  Ptrs ps;
  for (int i = 0; i < 14; i++){ ps.p[i] = d_in[i]; ps.sz[i] = in_sizes[i]; }
  probe_dtypes<<<14, 64, 0, stream>>>(ps, flags);

  cvt_all<<<28, 256, 0, stream>>>(qkv_b, proj_b, fc1_b, fc2_b, n1g, n1b, n2g, n2b, rpb, flags, prm);
  build_bm<<<48, 256, 0, stream>>>(p_rpb, bm_g);

  transpose_k<<<(384*1152+255)/256, 256, 0, stream>>>(qkv_w,  qkv_wt, 384, 1152, flags, 1);
  transpose_k<<<(384*384 +255)/256, 256, 0, stream>>>(proj_w, proj_wt, 384, 384, flags, 3);
  transpose_k<<<(384*1536+255)/256, 256, 0, stream>>>(fc1_w,  fc1_wt, 384, 1536, flags, 10);
  transpose_k<<<(1536*384+255)/256, 256, 0, stream>>>(fc2_w,  fc2_wt, 1536, 384, flags, 12);

  // zero vt once (pad cols 49..63 must be finite-zero; epilogue never writes them)
  hipMemsetAsync(vts, 0, (size_t)attn_wins*12*32*64*2, stream);

  // attention phase
  int nch = 1024 / attn_wins;
  for (int c = 0; c < nch; c++){
    int win0 = c * attn_wins, row0 = win0 * 49;
    int mrows = attn_wins * 49;
    ln1_kernel<<<mrows, 128, 0, stream>>>(x, p_n1g, p_n1b, xw, flags, row0, win0);
    gemm_bt<<<dim3(mrows/128, 9), 256, 0, stream>>>(xw, qkv_wt, 384, EpiQKV{p_qkv_b, qs, ksp, vts});
    attn_kernel<<<attn_wins*12, 256, 0, stream>>>(qs, ksp, vts, bm_g, xw);  // o overwrites xw
    gemm_bt<<<dim3(mrows/128, 3), 256, 0, stream>>>(xw, proj_wt, 384, EpiProj{p_proj_b, x, out, flags, win0});
  }

  // MLP phase
  for (int r0 = 0; r0 < M_ROWS; r0 += mlp_rows){
    ln2_kernel<<<mlp_rows, 128, 0, stream>>>(out, p_n2g, p_n2b, xn, r0);
    gemm_bt<<<dim3(mlp_rows/128, 12), 256, 0, stream>>>(xn, fc1_wt, 384, EpiFC1{p_fc1_b, hid});
    gemm_bt<<<dim3(mlp_rows/128, 3),  256, 0, stream>>>(hid, fc2_wt, 1536,
        EpiFC2{p_fc2_b, out, out, (size_t)r0});
  }
}

// Round 9
// 777.467 us; speedup vs baseline: 1.9113x; 1.0434x over previous
//
#include <hip/hip_runtime.h>
#include <hip/hip_bf16.h>
#include <math.h>

typedef unsigned short u16;
typedef __bf16 bf16x8 __attribute__((ext_vector_type(8)));
typedef float f32x4 __attribute__((ext_vector_type(4)));

#define M_ROWS 50176      // B*H*W = 64*28*28
#define SCALE_ 0.17677669529663687f

__device__ __forceinline__ float bf2f(u16 x){
  union { unsigned u; float f; } c; c.u = ((unsigned)x) << 16; return c.f;
}
__device__ __forceinline__ u16 f2bf(float f){
  union { float f; unsigned u; } c; c.f = f;
  unsigned u = c.u;
  u += 0x7fffu + ((u >> 16) & 1u);   // RNE
  return (u16)(u >> 16);
}
// isbf: 1 -> array is bf16, 0 -> fp32
__device__ __forceinline__ float ldf(const void* p, size_t i, int isbf){
  return isbf ? bf2f(((const u16*)p)[i]) : ((const float*)p)[i];
}

// direct global->LDS DMA, 16 B per lane; LDS dest = wave-uniform base + lane*16
__device__ __forceinline__ void glds16(const u16* g, u16* l){
  __builtin_amdgcn_global_load_lds(
      (__attribute__((address_space(1))) void*)(g),
      (__attribute__((address_space(3))) void*)(unsigned int)(unsigned long long)(l),
      16, 0, 0);
}

// ---- per-input dtype probe (proven r6) ----
struct Ptrs { const void* p[14]; int sz[14]; };
__global__ __launch_bounds__(64) void probe_dtypes(Ptrs ps, int* flags){
  int i = blockIdx.x;
  const unsigned* w = (const unsigned*)ps.p[i];
  int nw = ps.sz[i] >> 1;
  if (nw < 1) nw = 1;
  int stride = nw >> 6; if (!stride) stride = 1;
  int lane = threadIdx.x;
  long idx = (long)lane * stride; if (idx >= nw) idx = nw - 1;
  unsigned v = w[idx];
  unsigned L = v & 0xFFFFu;
  int lexp = (int)((L >> 7) & 0xFF);
  bool vb = (L != 0) && (lexp >= 100) && (lexp <= 141);
  bool vf = (!vb) && (v != 0);
  unsigned long long mb = __ballot(vb), mf = __ballot(vf);
  if (lane == 0) flags[i] = (__popcll(mb) >= __popcll(mf)) ? 1 : 0;
}

// ---- param conversion: all 1-D inputs -> fp32 block in ws ----
__global__ void cvt_all(const void* qkv_b, const void* proj_b, const void* fc1_b, const void* fc2_b,
                        const void* n1g, const void* n1b, const void* n2g, const void* n2b,
                        const void* rpb, const int* __restrict__ flags, float* dst){
  int i = blockIdx.x * 256 + threadIdx.x;
  if (i >= 7020) return;
  const void* src; int loc, fi;
  if      (i < 1152){ src = qkv_b; loc = i;        fi = 2; }
  else if (i < 1536){ src = proj_b; loc = i - 1152; fi = 4; }
  else if (i < 3072){ src = fc1_b; loc = i - 1536; fi = 11; }
  else if (i < 3456){ src = fc2_b; loc = i - 3072; fi = 13; }
  else if (i < 3840){ src = n1g;  loc = i - 3456; fi = 6; }
  else if (i < 4224){ src = n1b;  loc = i - 3840; fi = 7; }
  else if (i < 4608){ src = n2g;  loc = i - 4224; fi = 8; }
  else if (i < 4992){ src = n2b;  loc = i - 4608; fi = 9; }
  else              { src = rpb;  loc = i - 4992; fi = 5; }
  dst[i] = ldf(src, loc, flags[fi]);
}

// ---- weight transpose: in (K,N) either dtype -> out (N,K) bf16 ----
__global__ void transpose_k(const void* __restrict__ in, u16* __restrict__ out, int K, int N,
                            const int* __restrict__ flags, int fi){
  int tid = blockIdx.x * 256 + threadIdx.x;
  if (tid < K * N){
    int n = tid / K, k = tid - n * K;
    out[tid] = f2bf(ldf(in, (size_t)k * N + n, flags[fi]));
  }
}

// ---- bias+mask table: bm[wtype(4)][head(12)][64][64] bf16 ----
__global__ __launch_bounds__(256) void build_bm(const float* __restrict__ rpbf, u16* __restrict__ bm_g){
  int wt = blockIdx.x / 12, head = blockIdx.x - wt*12;
  u16* dst = bm_g + (size_t)blockIdx.x * 4096;
  bool he = (wt & 2), we = (wt & 1);
  for (int e = threadIdx.x; e < 4096; e += 256){
    int i = e >> 6, j = e & 63;
    float val;
    if (i >= 49) val = 0.f;
    else if (j >= 49) val = -1e9f;
    else {
      int ir = i/7, ic = i - ir*7, jr = j/7, jc = j - jr*7;
      int idx = (ir - jr + 6)*13 + (ic - jc + 6);
      val = rpbf[idx*12 + head];
      int li = (he ? (ir < 4 ? 1 : 2) : 0)*3 + (we ? (ic < 4 ? 1 : 2) : 0);
      int lj = (he ? (jr < 4 ? 1 : 2) : 0)*3 + (we ? (jc < 4 ? 1 : 2) : 0);
      if (li != lj) val -= 100.f;
    }
    dst[e] = f2bf(val);
  }
}

// ---- LN1 + shift + window partition for rows [row0, row0+grid) ----
__global__ __launch_bounds__(128) void ln1_kernel(const void* __restrict__ x, const float* __restrict__ g,
                                                  const float* __restrict__ bt, u16* __restrict__ xw,
                                                  const int* __restrict__ flags, int row0, int win0){
  int row = row0 + blockIdx.x;
  int bf = flags[0];
  size_t base = (size_t)row * 384;
  int t = threadIdx.x;
  float v0 = ldf(x, base + t, bf), v1 = ldf(x, base + t + 128, bf), v2 = ldf(x, base + t + 256, bf);
  float s = v0+v1+v2;
  float q = v0*v0+v1*v1+v2*v2;
  #pragma unroll
  for (int off = 32; off; off >>= 1){ s += __shfl_down(s, off); q += __shfl_down(q, off); }
  __shared__ float red[2][2];
  if ((t & 63) == 0){ red[t>>6][0] = s; red[t>>6][1] = q; }
  __syncthreads();
  float S = red[0][0] + red[1][0], Q = red[0][1] + red[1][1];
  float mu = S * (1.f/384.f);
  float var = Q * (1.f/384.f) - mu*mu;
  float rs = rsqrtf(var + 1e-5f);
  int b = row / 784; int hw = row - b*784; int h = hw / 28; int w = hw - h*28;
  int hs = h - 3; if (hs < 0) hs += 28;
  int ws = w - 3; if (ws < 0) ws += 28;
  int win = b*16 + (hs/7)*4 + (ws/7);
  int n = (hs%7)*7 + (ws%7);
  u16* orow = xw + ((size_t)(win - win0)*49 + n) * 384;
  orow[t]     = f2bf((v0 - mu)*rs*g[t]     + bt[t]);
  orow[t+128] = f2bf((v1 - mu)*rs*g[t+128] + bt[t+128]);
  orow[t+256] = f2bf((v2 - mu)*rs*g[t+256] + bt[t+256]);
}

// ---- LN2: x1 fp32 (d_out) rows [row0, row0+grid) -> xn bf16 local ----
__global__ __launch_bounds__(128) void ln2_kernel(const float* __restrict__ x, const float* __restrict__ g,
                                                  const float* __restrict__ bt, u16* __restrict__ xn, int row0){
  int row = row0 + blockIdx.x;
  const float* xr = x + (size_t)row * 384;
  int t = threadIdx.x;
  float v0 = xr[t], v1 = xr[t+128], v2 = xr[t+256];
  float s = v0+v1+v2;
  float q = v0*v0+v1*v1+v2*v2;
  #pragma unroll
  for (int off = 32; off; off >>= 1){ s += __shfl_down(s, off); q += __shfl_down(q, off); }
  __shared__ float red[2][2];
  if ((t & 63) == 0){ red[t>>6][0] = s; red[t>>6][1] = q; }
  __syncthreads();
  float S = red[0][0] + red[1][0], Q = red[0][1] + red[1][1];
  float mu = S * (1.f/384.f);
  float var = Q * (1.f/384.f) - mu*mu;
  float rs = rsqrtf(var + 1e-5f);
  u16* orow = xn + (size_t)blockIdx.x * 384;
  orow[t]     = f2bf((v0 - mu)*rs*g[t]     + bt[t]);
  orow[t+128] = f2bf((v1 - mu)*rs*g[t+128] + bt[t+128]);
  orow[t+256] = f2bf((v2 - mu)*rs*g[t+256] + bt[t+256]);
}

// ---- 128x128x32 MFMA GEMM with global_load_lds staging + XOR-swizzled LDS ----
// LDS tile [128 rows][32 u16] unpadded; chunk (row,kq) lives at row*4 + (kq ^ swz(row)),
// swz(row) = (row ^ (row>>2)) & 3  -> DMA-compatible lane-linear writes, 2-way reads (free).
template<class Epi>
__global__ __launch_bounds__(256) void gemm_bt(const u16* __restrict__ A, const u16* __restrict__ Bt,
                                               int K, Epi epi){
  __shared__ __align__(16) u16 lds_a[128*32];
  __shared__ __align__(16) u16 lds_b[128*32];
  const int tid = threadIdx.x;
  const int lane = tid & 63, wid = tid >> 6;
  const int wm = wid >> 1, wn = wid & 1;
  const int quad = lane >> 4, l16 = lane & 15;
  const int m0 = blockIdx.x * 128, n0 = blockIdx.y * 128;

  // staging addresses (loop-invariant): wave wid loads rows [wid*32, wid*32+32)
  const int lrow = lane >> 2, lkq = lane & 3;
  const int r0 = wid*32 + lrow, r1 = r0 + 16;
  const int s0 = (r0 ^ (r0 >> 2)) & 3, s1 = (r1 ^ (r1 >> 2)) & 3;
  const u16* gA0 = A  + (size_t)(m0 + r0)*K + ((lkq ^ s0) << 3);
  const u16* gA1 = A  + (size_t)(m0 + r1)*K + ((lkq ^ s1) << 3);
  const u16* gB0 = Bt + (size_t)(n0 + r0)*K + ((lkq ^ s0) << 3);
  const u16* gB1 = Bt + (size_t)(n0 + r1)*K + ((lkq ^ s1) << 3);
  u16* lA0 = &lds_a[(wid*32     )*32];
  u16* lA1 = &lds_a[(wid*32 + 16)*32];
  u16* lB0 = &lds_b[(wid*32     )*32];
  u16* lB1 = &lds_b[(wid*32 + 16)*32];

  // fragment read addresses (loop-invariant, swizzled)
  const u16* pa[4]; const u16* pb[4];
  #pragma unroll
  for (int i = 0; i < 4; i++){
    int ra = wm*64 + i*16 + l16;
    pa[i] = &lds_a[ra*32 + ((quad ^ ((ra ^ (ra >> 2)) & 3)) << 3)];
    int rb = wn*64 + i*16 + l16;
    pb[i] = &lds_b[rb*32 + ((quad ^ ((rb ^ (rb >> 2)) & 3)) << 3)];
  }

  f32x4 acc[4][4];
  #pragma unroll
  for (int i = 0; i < 4; i++)
    #pragma unroll
    for (int j = 0; j < 4; j++){ f32x4 z = {0.f,0.f,0.f,0.f}; acc[i][j] = z; }

  for (int k0 = 0; k0 < K; k0 += 32){
    glds16(gA0 + k0, lA0);
    glds16(gA1 + k0, lA1);
    glds16(gB0 + k0, lB0);
    glds16(gB1 + k0, lB1);
    __syncthreads();
    bf16x8 af[4], bfr[4];
    #pragma unroll
    for (int i = 0; i < 4; i++){
      af[i]  = *(const bf16x8*)pa[i];
      bfr[i] = *(const bf16x8*)pb[i];
    }
    #pragma unroll
    for (int i = 0; i < 4; i++)
      #pragma unroll
      for (int j = 0; j < 4; j++)
        acc[i][j] = __builtin_amdgcn_mfma_f32_16x16x32_bf16(af[i], bfr[j], acc[i][j], 0, 0, 0);
    __syncthreads();
  }
  #pragma unroll
  for (int i = 0; i < 4; i++)
    #pragma unroll
    for (int j = 0; j < 4; j++)
      #pragma unroll
      for (int r = 0; r < 4; r++){
        int row = m0 + wm*64 + i*16 + quad*4 + r;
        int col = n0 + wn*64 + j*16 + l16;
        epi(acc[i][j][r], row, col);
      }
}

// ---- epilogues ----
struct EpiQKV {   // rows LOCAL to chunk; v stored TRANSPOSED+padded: [wh][hd(32)][64]
  const float* bias; u16 *q, *k, *vt;
  __device__ __forceinline__ void operator()(float acc, int row, int col) const {
    float val = acc + bias[col];
    int which = col / 384; int cc = col - which*384;
    int head = cc >> 5, hd = cc & 31;
    int win = row / 49; int n = row - win*49;
    if (which == 0){
      q[((size_t)(win*12 + head)*49 + n)*32 + hd] = f2bf(val * SCALE_);
    } else if (which == 1){
      k[((size_t)(win*12 + head)*49 + n)*32 + hd] = f2bf(val);
    } else {
      vt[((size_t)(win*12 + head)*32 + hd)*64 + n] = f2bf(val);
    }
  }
};

struct EpiProj {  // rows local; win0 = global window offset; x1 = d_out (fp32 residual)
  const float* bias; const void* x; float* x1; const int* flags; int win0;
  __device__ __forceinline__ void operator()(float acc, int row, int col) const {
    int win = win0 + row / 49; int n = row - (row/49)*49;
    int b = win >> 4; int w16 = win & 15;
    int wh = w16 >> 2, ww = w16 & 3;
    int r = n / 7, cn = n - r*7;
    int h = wh*7 + r + 3; if (h >= 28) h -= 28;
    int w = ww*7 + cn + 3; if (w >= 28) w -= 28;
    size_t idx = ((size_t)b*784 + h*28 + w)*384 + col;
    x1[idx] = acc + bias[col] + ldf(x, idx, flags[0]);
  }
};

struct EpiFC1 {
  const float* bias; u16* hid;
  __device__ __forceinline__ void operator()(float acc, int row, int col) const {
    float x = acc + bias[col];
    float g = 0.5f * x * (1.0f + erff(x * 0.70710678118654752f));
    hid[(size_t)row*1536 + col] = f2bf(g);
  }
};

struct EpiFC2 {   // x1 == out == d_out fp32; same lane reads+writes idx
  const float* bias; const float* x1; float* out; size_t row_off;
  __device__ __forceinline__ void operator()(float acc, int row, int col) const {
    size_t idx = (row_off + (size_t)row)*384 + col;
    out[idx] = x1[idx] + acc + bias[col];
  }
};

// ---- attention v2 (r8-proven): direct-global frags, bm table, in-register softmax ----
__global__ __launch_bounds__(256) void attn_kernel(const u16* __restrict__ q, const u16* __restrict__ kk,
                                                   const u16* __restrict__ vt_g, const u16* __restrict__ bm_g,
                                                   u16* __restrict__ o){
  __shared__ __align__(16) u16 ps[64*72];
  __shared__ __align__(16) u16 bms[64*72];
  int blk = blockIdx.x;
  int win = blk / 12, head = blk - win*12;
  int tid = threadIdx.x, lane = tid & 63, wid = tid >> 6;
  int quad = lane >> 4, l16 = lane & 15;
  size_t base = (size_t)blk * 1568;

  int w16 = win & 15;
  int wt = (((w16 >> 2) == 3) ? 2 : 0) + (((w16 & 3) == 3) ? 1 : 0);
  const u16* bsrc = bm_g + (size_t)(wt*12 + head) * 4096;
  #pragma unroll
  for (int it = 0; it < 2; it++){
    int e = tid + it*256;
    int row = e >> 3, c8 = (e & 7) << 3;
    *(uint4*)&bms[row*72 + c8] = *(const uint4*)&bsrc[row*64 + c8];
  }

  int i0 = wid * 16;
  bf16x8 aq = *(const bf16x8*)&q[base + (size_t)(i0 + l16)*32 + quad*8];
  f32x4 zero = {0.f,0.f,0.f,0.f};
  f32x4 c[4];
  #pragma unroll
  for (int nt = 0; nt < 4; nt++){
    bf16x8 bk = *(const bf16x8*)&kk[base + (size_t)(nt*16 + l16)*32 + quad*8];
    c[nt] = __builtin_amdgcn_mfma_f32_16x16x32_bf16(aq, bk, zero, 0, 0, 0);
  }
  __syncthreads();

  #pragma unroll
  for (int r = 0; r < 4; r++){
    int i = i0 + quad*4 + r;
    float v0 = c[0][r] + bf2f(bms[i*72 +      l16]);
    float v1 = c[1][r] + bf2f(bms[i*72 + 16 + l16]);
    float v2 = c[2][r] + bf2f(bms[i*72 + 32 + l16]);
    float v3 = c[3][r] + bf2f(bms[i*72 + 48 + l16]);
    float m = fmaxf(fmaxf(v0, v1), fmaxf(v2, v3));
    #pragma unroll
    for (int off = 1; off < 16; off <<= 1) m = fmaxf(m, __shfl_xor(m, off));
    float e0 = __expf(v0 - m), e1 = __expf(v1 - m), e2 = __expf(v2 - m), e3 = __expf(v3 - m);
    float s = e0 + e1 + e2 + e3;
    #pragma unroll
    for (int off = 1; off < 16; off <<= 1) s += __shfl_xor(s, off);
    float inv = 1.f / s;
    ps[i*72 +      l16] = f2bf(e0 * inv);
    ps[i*72 + 16 + l16] = f2bf(e1 * inv);
    ps[i*72 + 32 + l16] = f2bf(e2 * inv);
    ps[i*72 + 48 + l16] = f2bf(e3 * inv);
  }

  size_t vbase = (size_t)blk * 2048;
  f32x4 accO[2] = {{0.f,0.f,0.f,0.f},{0.f,0.f,0.f,0.f}};
  #pragma unroll
  for (int s2 = 0; s2 < 2; s2++){
    bf16x8 ap = *(const bf16x8*)&ps[(i0 + l16)*72 + s2*32 + quad*8];
    #pragma unroll
    for (int nt = 0; nt < 2; nt++){
      bf16x8 bv = *(const bf16x8*)&vt_g[vbase + (size_t)(nt*16 + l16)*64 + s2*32 + quad*8];
      accO[nt] = __builtin_amdgcn_mfma_f32_16x16x32_bf16(ap, bv, accO[nt], 0, 0, 0);
    }
  }
  #pragma unroll
  for (int nt = 0; nt < 2; nt++)
    #pragma unroll
    for (int r = 0; r < 4; r++){
      int i = i0 + quad*4 + r;
      if (i < 49)
        o[((size_t)win*49 + i)*384 + head*32 + nt*16 + l16] = f2bf(accO[nt][r]);
    }
}

// ---- launch ----
extern "C" void kernel_launch(void* const* d_in, const int* in_sizes, int n_in,
                              void* d_out, int out_size, void* d_ws, size_t ws_size,
                              hipStream_t stream){
  (void)n_in; (void)out_size;
  const void* x      = d_in[0];
  const void* qkv_w  = d_in[1];
  const void* qkv_b  = d_in[2];
  const void* proj_w = d_in[3];
  const void* proj_b = d_in[4];
  const void* rpb    = d_in[5];
  const void* n1g    = d_in[6];
  const void* n1b    = d_in[7];
  const void* n2g    = d_in[8];
  const void* n2b    = d_in[9];
  const void* fc1_w  = d_in[10];
  const void* fc1_b  = d_in[11];
  const void* fc2_w  = d_in[12];
  const void* fc2_b  = d_in[13];
  float* out = (float*)d_out;   // fp32 output (verified r6)

  char* ws = (char*)d_ws;
  size_t off = 0;
  auto alloc = [&](size_t bytes)->void*{
    void* p = ws + off; off = (off + bytes + 255) & ~(size_t)255; return p;
  };
  int*   flags  = (int*)  alloc(14*4);
  float* prm    = (float*)alloc(7020*4);
  u16*   bm_g   = (u16*)  alloc((size_t)48*4096*2);
  u16*   qkv_wt = (u16*)  alloc((size_t)384*1152*2);
  u16*   proj_wt= (u16*)  alloc((size_t)384*384*2);
  u16*   fc1_wt = (u16*)  alloc((size_t)384*1536*2);
  u16*   fc2_wt = (u16*)  alloc((size_t)1536*384*2);
  size_t fixed_end = off;
  size_t avail = (ws_size > fixed_end) ? ws_size - fixed_end : 0;

  int attn_wins = 128;
  if      ((size_t)1024*162048 <= avail) attn_wins = 1024;
  else if ((size_t)512 *162048 <= avail) attn_wins = 512;
  else if ((size_t)256 *162048 <= avail) attn_wins = 256;

  int mlp_rows = 1792;
  if      ((size_t)50176*3840 <= avail) mlp_rows = 50176;
  else if ((size_t)25088*3840 <= avail) mlp_rows = 25088;
  else if ((size_t)12544*3840 <= avail) mlp_rows = 12544;
  else if ((size_t)6272 *3840 <= avail) mlp_rows = 6272;

  u16* scr = (u16*)(ws + fixed_end);
  u16* xw  = scr;
  u16* qs  = scr + (size_t)attn_wins*49*384;
  u16* ksp = qs  + (size_t)attn_wins*12*49*32;
  u16* vts = ksp + (size_t)attn_wins*12*49*32;
  u16* xn  = scr;
  u16* hid = scr + (size_t)mlp_rows*384;

  float* p_qkv_b = prm;
  float* p_proj_b= prm + 1152;
  float* p_fc1_b = prm + 1536;
  float* p_fc2_b = prm + 3072;
  float* p_n1g   = prm + 3456;
  float* p_n1b   = prm + 3840;
  float* p_n2g   = prm + 4224;
  float* p_n2b   = prm + 4608;
  float* p_rpb   = prm + 4992;

  Ptrs ps;
  for (int i = 0; i < 14; i++){ ps.p[i] = d_in[i]; ps.sz[i] = in_sizes[i]; }
  probe_dtypes<<<14, 64, 0, stream>>>(ps, flags);

  cvt_all<<<28, 256, 0, stream>>>(qkv_b, proj_b, fc1_b, fc2_b, n1g, n1b, n2g, n2b, rpb, flags, prm);
  build_bm<<<48, 256, 0, stream>>>(p_rpb, bm_g);

  transpose_k<<<(384*1152+255)/256, 256, 0, stream>>>(qkv_w,  qkv_wt, 384, 1152, flags, 1);
  transpose_k<<<(384*384 +255)/256, 256, 0, stream>>>(proj_w, proj_wt, 384, 384, flags, 3);
  transpose_k<<<(384*1536+255)/256, 256, 0, stream>>>(fc1_w,  fc1_wt, 384, 1536, flags, 10);
  transpose_k<<<(1536*384+255)/256, 256, 0, stream>>>(fc2_w,  fc2_wt, 1536, 384, flags, 12);

  hipMemsetAsync(vts, 0, (size_t)attn_wins*12*32*64*2, stream);

  int nch = 1024 / attn_wins;
  for (int c = 0; c < nch; c++){
    int win0 = c * attn_wins, row0 = win0 * 49;
    int mrows = attn_wins * 49;
    ln1_kernel<<<mrows, 128, 0, stream>>>(x, p_n1g, p_n1b, xw, flags, row0, win0);
    gemm_bt<<<dim3(mrows/128, 9), 256, 0, stream>>>(xw, qkv_wt, 384, EpiQKV{p_qkv_b, qs, ksp, vts});
    attn_kernel<<<attn_wins*12, 256, 0, stream>>>(qs, ksp, vts, bm_g, xw);
    gemm_bt<<<dim3(mrows/128, 3), 256, 0, stream>>>(xw, proj_wt, 384, EpiProj{p_proj_b, x, out, flags, win0});
  }

  for (int r0 = 0; r0 < M_ROWS; r0 += mlp_rows){
    ln2_kernel<<<mlp_rows, 128, 0, stream>>>(out, p_n2g, p_n2b, xn, r0);
    gemm_bt<<<dim3(mlp_rows/128, 12), 256, 0, stream>>>(xn, fc1_wt, 384, EpiFC1{p_fc1_b, hid});
    gemm_bt<<<dim3(mlp_rows/128, 3),  256, 0, stream>>>(hid, fc2_wt, 1536,
        EpiFC2{p_fc2_b, out, out, (size_t)r0});
  }
}